// Round 5
// baseline (664.994 us; speedup 1.0000x reference)
//
#include <hip/hip_runtime.h>
#include <stdint.h>

// LSTM2Encoder: x=emb[ids]; h0=lstm0(x); h1=lstm1(h0); out=relu(h1@Wlin^T+b)
// R7: R6 structure with the readback bug fixed. BM=256, BN=256, BK=32,
// 512 thr = 8 waves (2x4), wave tile 128x64 (acc 8x4). Static 64KB LDS:
// two 32KB buffers (A 16KB + B 16KB each). Per K-tile (16): p0 = 12
// ds_reads + 4-stage gl2lds(nxt) -> barrier -> lgkm(0) -> 16 MFMA;
// p1 = 16 MFMA -> vmcnt(0) -> barrier. setprio(1) around MFMA clusters.
// R5/R6 BUG was here: BN=256 slice is 64 units = 32 halfs/thread in the
// MODE-0 readback; R5/R6 moved only 16 halfs -> half of H0f/H1f stale ->
// absmax 468. Now 4x uint4v per thread. Also launch_bounds(512,1): the
// old (512,2) clamped VGPR to 128 = guaranteed acc spill.

typedef _Float16 half8 __attribute__((ext_vector_type(8)));
typedef __attribute__((ext_vector_type(4))) float float4v;
typedef __attribute__((ext_vector_type(4))) unsigned int uint4v;

__device__ __forceinline__ float sigmoidf_(float x) { return 1.0f / (1.0f + __expf(-x)); }
__device__ __forceinline__ float tanhf_(float x) { return 1.0f - 2.0f / (__expf(2.0f * x) + 1.0f); }

__device__ __forceinline__ void gl2lds16(const void* g, void* l) {
  __builtin_amdgcn_global_load_lds(
      (const __attribute__((address_space(1))) void*)g,
      (__attribute__((address_space(3))) void*)l, 16, 0, 0);
}

// ---------------- prep: emb->fp16; weights permuted+cast; biases folded ----
// W'[4j+g][k] = W[g*512+j][k]  (g in {i,f,g,o});  b'[4j+g] = b_ih[n]+b_hh[n]
__global__ __launch_bounds__(256) void prep_kernel(
    const float* __restrict__ emb,
    const float* __restrict__ W0, const float* __restrict__ bi0, const float* __restrict__ bh0,
    const float* __restrict__ W1, const float* __restrict__ bi1, const float* __restrict__ bh1,
    const float* __restrict__ WL,
    _Float16* __restrict__ Ef,
    _Float16* __restrict__ W0f, _Float16* __restrict__ W1f, _Float16* __restrict__ WLf,
    float* __restrict__ b0p, float* __restrict__ b1p)
{
  int id = blockIdx.x * 256 + threadIdx.x;
  if (id < 3216448) {                               // emb cast (50257*512/8)
    const float* s = emb + (size_t)id * 8;
    float4v v0 = *(const float4v*)s;
    float4v v1 = *(const float4v*)(s + 4);
    union { _Float16 h[8]; uint4v u; } P;
#pragma unroll
    for (int e = 0; e < 4; ++e) { P.h[e] = (_Float16)v0[e]; P.h[4 + e] = (_Float16)v1[e]; }
    *(uint4v*)(Ef + (size_t)id * 8) = P.u;
  } else if (id < 3347520) {                        // W0 permute+cast (2048*512/8)
    int u = id - 3216448;
    int np = u >> 6, k0 = (u & 63) << 3;
    int n = ((np & 3) << 9) | (np >> 2);
    const float* s = W0 + n * 512 + k0;
    float4v v0 = *(const float4v*)s;
    float4v v1 = *(const float4v*)(s + 4);
    union { _Float16 h[8]; uint4v u; } P;
#pragma unroll
    for (int e = 0; e < 4; ++e) { P.h[e] = (_Float16)v0[e]; P.h[4 + e] = (_Float16)v1[e]; }
    *(uint4v*)(W0f + np * 512 + k0) = P.u;
  } else if (id < 3478592) {                        // W1
    int u = id - 3347520;
    int np = u >> 6, k0 = (u & 63) << 3;
    int n = ((np & 3) << 9) | (np >> 2);
    const float* s = W1 + n * 512 + k0;
    float4v v0 = *(const float4v*)s;
    float4v v1 = *(const float4v*)(s + 4);
    union { _Float16 h[8]; uint4v u; } P;
#pragma unroll
    for (int e = 0; e < 4; ++e) { P.h[e] = (_Float16)v0[e]; P.h[4 + e] = (_Float16)v1[e]; }
    *(uint4v*)(W1f + np * 512 + k0) = P.u;
  } else if (id < 3511360) {                        // WL straight cast (512*512/8)
    int u = id - 3478592;
    const float* s = WL + (size_t)u * 8;
    float4v v0 = *(const float4v*)s;
    float4v v1 = *(const float4v*)(s + 4);
    union { _Float16 h[8]; uint4v u8; } P;
#pragma unroll
    for (int e = 0; e < 4; ++e) { P.h[e] = (_Float16)v0[e]; P.h[4 + e] = (_Float16)v1[e]; }
    *(uint4v*)(WLf + (size_t)u * 8) = P.u8;
  } else if (id < 3513408) {                        // b0 fold+permute
    int np = id - 3511360;
    int n = ((np & 3) << 9) | (np >> 2);
    b0p[np] = bi0[n] + bh0[n];
  } else if (id < 3515456) {                        // b1
    int np = id - 3513408;
    int n = ((np & 3) << 9) | (np >> 2);
    b1p[np] = bi1[n] + bh1[n];
  }
}

// ---------------- fused fp16 GEMM, 256x256 tile, BK=32, 2-phase dbuf ------
// 8 waves as 2x4 grid of 128x64 wave tiles. acc[i][j] = mfma(b[j], a[i], acc)
// -> acc rows = permuted-N (gates), cols = tokens.
// MODE 0: LSTM layer  -> h = sig(o)*tanh(sig(i)*tanh(g)), write h fp16
// MODE 1: final linear -> out = relu(acc + bias), float4 stores
template <int MODE>
__global__ __launch_bounds__(512, 1) void gemm_kernel(
    const _Float16* __restrict__ A, const int* __restrict__ ids,
    const _Float16* __restrict__ B, const float* __restrict__ bias,
    _Float16* __restrict__ Of, float* __restrict__ Out,
    int nbShift, int nbMask)
{
  __shared__ __align__(16) char smem[65536];        // 2 x (16KB A + 16KB B)
  const int T = threadIdx.x;
  const int lane = T & 63;
  const int wv = T >> 6;
  const int wrow = wv >> 2, wcol = wv & 3;          // 2x4 wave grid, 128x64 tiles

  // XCD-bijective swizzle (grid % 8 == 0 for all launches)
  const int nwg = (int)gridDim.x;
  const int bid = (int)blockIdx.x;
  const int swz = (bid & 7) * (nwg >> 3) + (bid >> 3);
  const int mb = swz >> nbShift;
  const int nb = swz & nbMask;
  const size_t t0 = (size_t)mb * 256;
  const int n0 = nb * 256;

  // staging (R4-proven swizzle): thread T stages rows r,r+128 of A and of B,
  // quad qg = (T&3) ^ ((r>>1)&3) (global-side pre-swizzle; LDS linear).
  const int r = T >> 2;                             // 0..127
  const int qg = (T & 3) ^ ((r >> 1) & 3);
  size_t ar0 = t0 + r, ar1 = t0 + 128 + r;
  if (ids) {
    ar0 = (size_t)(unsigned)ids[ar0]; ar1 = (size_t)(unsigned)ids[ar1];
  }
  const _Float16* pA0 = A + ar0 * 512 + qg * 8;
  const _Float16* pA1 = A + ar1 * 512 + qg * 8;
  const _Float16* pB0 = B + (size_t)(n0 + r) * 512 + qg * 8;
  const _Float16* pB1 = B + (size_t)(n0 + 128 + r) * 512 + qg * 8;

  // LDS dest byte offsets: A rows 0..127 at [0,8K), 128..255 at [8K,16K);
  // B same at +16K. Within a row (64B), slot T&3 holds global quad qg.
  const int d0 = T * 16;

#define STAGE(dst) do { \
    gl2lds16(pA0, (dst) + d0);         gl2lds16(pA1, (dst) + 8192 + d0); \
    gl2lds16(pB0, (dst) + 16384 + d0); gl2lds16(pB1, (dst) + 24576 + d0); \
    pA0 += 32; pA1 += 32; pB0 += 32; pB1 += 32; } while (0)

  // fragment read offsets (halfs, within a buffer); un-swizzle with qs
  const int m_ = lane & 15, qf = lane >> 4;
  const int qs = qf ^ ((m_ >> 1) & 3);
  const int offA = (wrow * 128 + m_) * 32 + qs * 8;
  const int offB = 8192 + (wcol * 64 + m_) * 32 + qs * 8;

  float4v acc[8][4];
#pragma unroll
  for (int i = 0; i < 8; ++i)
#pragma unroll
    for (int j = 0; j < 4; ++j)
      acc[i][j] = (float4v){0.f, 0.f, 0.f, 0.f};

  // prologue: stage K-tile 0 into buf0, drain, fence, sync
  char* b0c = smem;
  char* b1c = smem + 32768;
  STAGE(b0c);
  asm volatile("s_waitcnt vmcnt(0)" ::: "memory");
  __builtin_amdgcn_sched_barrier(0);
  __builtin_amdgcn_s_barrier();

  const _Float16* cur = (const _Float16*)b0c;
  char* nxt = b1c;

#pragma unroll 2
  for (int t = 0; t < 16; ++t) {
    // ---- p0: all 12 ds_reads + stage(t+1); MFMA j0,j1 ----
    half8 a[8], b[4];
#pragma unroll
    for (int i = 0; i < 8; ++i) a[i] = *(const half8*)(cur + offA + i * 512);
#pragma unroll
    for (int j = 0; j < 4; ++j) b[j] = *(const half8*)(cur + offB + j * 512);
    if (t < 15) STAGE(nxt);
    __builtin_amdgcn_s_barrier();
    asm volatile("s_waitcnt lgkmcnt(0)" ::: "memory");
    __builtin_amdgcn_sched_barrier(0);
    __builtin_amdgcn_s_setprio(1);
#pragma unroll
    for (int i = 0; i < 8; ++i) {
      acc[i][0] = __builtin_amdgcn_mfma_f32_16x16x32_f16(b[0], a[i], acc[i][0], 0, 0, 0);
      acc[i][1] = __builtin_amdgcn_mfma_f32_16x16x32_f16(b[1], a[i], acc[i][1], 0, 0, 0);
    }
    __builtin_amdgcn_s_setprio(0);
    __builtin_amdgcn_sched_barrier(0);
    __builtin_amdgcn_s_barrier();
    // ---- p1: MFMA j2,j3; tile-boundary drain; swap ----
    __builtin_amdgcn_s_setprio(1);
#pragma unroll
    for (int i = 0; i < 8; ++i) {
      acc[i][2] = __builtin_amdgcn_mfma_f32_16x16x32_f16(b[2], a[i], acc[i][2], 0, 0, 0);
      acc[i][3] = __builtin_amdgcn_mfma_f32_16x16x32_f16(b[3], a[i], acc[i][3], 0, 0, 0);
    }
    __builtin_amdgcn_s_setprio(0);
    __builtin_amdgcn_sched_barrier(0);
    if (t < 15) { asm volatile("s_waitcnt vmcnt(0)" ::: "memory"); }
    __builtin_amdgcn_sched_barrier(0);
    __builtin_amdgcn_s_barrier();
    const _Float16* tc = cur; cur = (const _Float16*)nxt; nxt = (char*)tc;
  }
#undef STAGE

  // bias: acc rows are permuted-N -> 4 consecutive rows per lane = one float4
  float4v bq[4];
#pragma unroll
  for (int j = 0; j < 4; ++j)
    bq[j] = *(const float4v*)(bias + n0 + wcol * 64 + j * 16 + qf * 4);

  if (MODE == 0) {
    _Float16* hT = (_Float16*)smem;                 // 256 x 72 halfs (144B rows)
    const int ub = wcol * 16 + qf;                  // + j*4 -> unit col 0..63
#pragma unroll
    for (int i = 0; i < 8; ++i) {
      const int trow = wrow * 128 + i * 16 + m_;
#pragma unroll
      for (int j = 0; j < 4; ++j) {
        // regs = gates {i,f,g,o} of unit (ub+j*4); f unused (c_prev=0)
        float yi = acc[i][j][0] + bq[j][0];
        float yg = acc[i][j][2] + bq[j][2];
        float yo = acc[i][j][3] + bq[j][3];
        float cc = sigmoidf_(yi) * tanhf_(yg);
        float hh = sigmoidf_(yo) * tanhf_(cc);
        hT[trow * 72 + ub + j * 4] = (_Float16)hh;
      }
    }
    __syncthreads();
    // readback: thread pair owns one token row; each thread moves 32 halfs
    // (hf*32 .. hf*32+31) = half the 64-unit slice. 4x ds_read_b128 +
    // 4x global_store_dwordx4. (R5/R6 bug: only 16 halfs -> stale output.)
    const int tok = T >> 1, hf = T & 1;
    const _Float16* src = hT + tok * 72 + hf * 32;
    uint4v v0 = *(const uint4v*)(src);
    uint4v v1 = *(const uint4v*)(src + 8);
    uint4v v2 = *(const uint4v*)(src + 16);
    uint4v v3 = *(const uint4v*)(src + 24);
    _Float16* dst = Of + (t0 + tok) * 512 + (size_t)nb * 64 + hf * 32;
    *(uint4v*)dst = v0;
    *(uint4v*)(dst + 8) = v1;
    *(uint4v*)(dst + 16) = v2;
    *(uint4v*)(dst + 24) = v3;
  } else {
#pragma unroll
    for (int i = 0; i < 8; ++i) {
      const size_t row = t0 + wrow * 128 + i * 16 + m_;
#pragma unroll
      for (int j = 0; j < 4; ++j) {
        float4v v;
#pragma unroll
        for (int r2 = 0; r2 < 4; ++r2)
          v[r2] = fmaxf(acc[i][j][r2] + bq[j][r2], 0.0f);
        *(float4v*)(Out + row * 512 + (size_t)(n0 + wcol * 64 + j * 16 + qf * 4)) = v;
      }
    }
  }
}

extern "C" void kernel_launch(void* const* d_in, const int* in_sizes, int n_in,
                              void* d_out, int out_size, void* d_ws, size_t ws_size,
                              hipStream_t stream) {
  (void)in_sizes; (void)n_in; (void)out_size; (void)ws_size;
  const int*   ids   = (const int*)d_in[0];
  const float* emb   = (const float*)d_in[1];
  const float* W0    = (const float*)d_in[2];
  // d_in[3] = W_hh0 unused (h_prev = 0)
  const float* bi0   = (const float*)d_in[4];
  const float* bh0   = (const float*)d_in[5];
  const float* W1    = (const float*)d_in[6];
  // d_in[7] = W_hh1 unused
  const float* bi1   = (const float*)d_in[8];
  const float* bh1   = (const float*)d_in[9];
  const float* WL    = (const float*)d_in[10];
  const float* blin  = (const float*)d_in[11];
  float* out = (float*)d_out;

  char* ws = (char*)d_ws;
  const size_t MB = 1024 * 1024;
  _Float16* W0f = (_Float16*)(ws);                  // 2 MB
  _Float16* W1f = (_Float16*)(ws + 2 * MB);         // 2 MB
  _Float16* WLf = (_Float16*)(ws + 4 * MB);         // 0.5 MB
  float*    b0p = (float*)(ws + 4 * MB + 512 * 1024);
  float*    b1p = (float*)(ws + 4 * MB + 512 * 1024 + 8192);
  _Float16* Ef  = (_Float16*)(ws + 8 * MB);         // 51.5 MB (64 MB slot)
  _Float16* H1f = Ef;                               // Ef dead after layer 0
  _Float16* H0f = (_Float16*)(ws + 72 * MB);        // 64 MB
  // total ws use: 136 MB

  prep_kernel<<<13733, 256, 0, stream>>>(emb, W0, bi0, bh0, W1, bi1, bh1, WL,
                                         Ef, W0f, W1f, WLf, b0p, b1p);
  gemm_kernel<0><<<2048, 512, 0, stream>>>(Ef, ids, W0f, b0p, H0f, nullptr, 3, 7);
  gemm_kernel<0><<<2048, 512, 0, stream>>>(H0f, nullptr, W1f, b1p, H1f, nullptr, 3, 7);
  gemm_kernel<1><<<512, 512, 0, stream>>>(H1f, nullptr, WLf, blin, nullptr, out, 1, 1);
}

// Round 6
// 590.731 us; speedup vs baseline: 1.1257x; 1.1257x over previous
//
#include <hip/hip_runtime.h>
#include <stdint.h>

// LSTM2Encoder: x=emb[ids]; h0=lstm0(x); h1=lstm1(h0); out=relu(h1@Wlin^T+b)
// R8: vocab-table restructure. Zero LSTM state => out[t] = F(emb[ids[t]]):
// the whole network is a per-vocab-id function. Both LSTM-layer GEMMs run
// over the 50432-row (padded) vocab table with NO gather (0.77x FLOPs vs
// 65536 tokens); the ids gather moves to gemm<1>'s A-staging (same
// mechanism layer-0 used before). GEMM substrate = R3's proven 227-us
// kernel (256x128 tile, 8 waves 64x64, BK=32, simple 2-barrier loop,
// 64 VGPR) + XCD-bijective swizzle (R4: FETCH 252->46MB) + fp16 hT
// epilogue (smem 36.9->24KB -> up to 4 blocks/CU). Deep-pipeline variants
// (R4-R7) all measured slower than this substrate; dropped.

typedef _Float16 half8 __attribute__((ext_vector_type(8)));
typedef __attribute__((ext_vector_type(4))) float float4v;
typedef __attribute__((ext_vector_type(4))) unsigned int uint4v;

__device__ __forceinline__ float sigmoidf_(float x) { return 1.0f / (1.0f + __expf(-x)); }
__device__ __forceinline__ float tanhf_(float x) { return 1.0f - 2.0f / (__expf(2.0f * x) + 1.0f); }

__device__ __forceinline__ void gl2lds16(const void* g, void* l) {
  __builtin_amdgcn_global_load_lds(
      (const __attribute__((address_space(1))) void*)g,
      (__attribute__((address_space(3))) void*)l, 16, 0, 0);
}

// ---------------- prep: emb->fp16; weights permuted+cast; biases folded ----
// W'[4j+g][k] = W[g*512+j][k]  (g in {i,f,g,o});  b'[4j+g] = b_ih[n]+b_hh[n]
// Also zeroes Ef pad rows [50257,50432) so pad outputs stay finite.
__global__ __launch_bounds__(256) void prep_kernel(
    const float* __restrict__ emb,
    const float* __restrict__ W0, const float* __restrict__ bi0, const float* __restrict__ bh0,
    const float* __restrict__ W1, const float* __restrict__ bi1, const float* __restrict__ bh1,
    const float* __restrict__ WL,
    _Float16* __restrict__ Ef,
    _Float16* __restrict__ W0f, _Float16* __restrict__ W1f, _Float16* __restrict__ WLf,
    float* __restrict__ b0p, float* __restrict__ b1p)
{
  int id = blockIdx.x * 256 + threadIdx.x;
  if (id < 3216448) {                               // emb cast (50257*512/8)
    const float* s = emb + (size_t)id * 8;
    float4v v0 = *(const float4v*)s;
    float4v v1 = *(const float4v*)(s + 4);
    union { _Float16 h[8]; uint4v u; } P;
#pragma unroll
    for (int e = 0; e < 4; ++e) { P.h[e] = (_Float16)v0[e]; P.h[4 + e] = (_Float16)v1[e]; }
    *(uint4v*)(Ef + (size_t)id * 8) = P.u;
  } else if (id < 3347520) {                        // W0 permute+cast (2048*512/8)
    int u = id - 3216448;
    int np = u >> 6, k0 = (u & 63) << 3;
    int n = ((np & 3) << 9) | (np >> 2);
    const float* s = W0 + n * 512 + k0;
    float4v v0 = *(const float4v*)s;
    float4v v1 = *(const float4v*)(s + 4);
    union { _Float16 h[8]; uint4v u; } P;
#pragma unroll
    for (int e = 0; e < 4; ++e) { P.h[e] = (_Float16)v0[e]; P.h[4 + e] = (_Float16)v1[e]; }
    *(uint4v*)(W0f + np * 512 + k0) = P.u;
  } else if (id < 3478592) {                        // W1
    int u = id - 3347520;
    int np = u >> 6, k0 = (u & 63) << 3;
    int n = ((np & 3) << 9) | (np >> 2);
    const float* s = W1 + n * 512 + k0;
    float4v v0 = *(const float4v*)s;
    float4v v1 = *(const float4v*)(s + 4);
    union { _Float16 h[8]; uint4v u; } P;
#pragma unroll
    for (int e = 0; e < 4; ++e) { P.h[e] = (_Float16)v0[e]; P.h[4 + e] = (_Float16)v1[e]; }
    *(uint4v*)(W1f + np * 512 + k0) = P.u;
  } else if (id < 3511360) {                        // WL straight cast (512*512/8)
    int u = id - 3478592;
    const float* s = WL + (size_t)u * 8;
    float4v v0 = *(const float4v*)s;
    float4v v1 = *(const float4v*)(s + 4);
    union { _Float16 h[8]; uint4v u8; } P;
#pragma unroll
    for (int e = 0; e < 4; ++e) { P.h[e] = (_Float16)v0[e]; P.h[4 + e] = (_Float16)v1[e]; }
    *(uint4v*)(WLf + (size_t)u * 8) = P.u8;
  } else if (id < 3513408) {                        // b0 fold+permute
    int np = id - 3511360;
    int n = ((np & 3) << 9) | (np >> 2);
    b0p[np] = bi0[n] + bh0[n];
  } else if (id < 3515456) {                        // b1
    int np = id - 3513408;
    int n = ((np & 3) << 9) | (np >> 2);
    b1p[np] = bi1[n] + bh1[n];
  } else if (id < 3526656) {                        // zero Ef pad rows (175x512)
    int u = id - 3515456;
    *(uint4v*)(Ef + 25731584 + (size_t)u * 8) = (uint4v){0u, 0u, 0u, 0u};
  }
}

// ---------------- fused fp16 GEMM, 256x128 tile, BK=32 (R3 substrate) ------
// 8 waves as 4x2 grid of 64x64 wave tiles. acc[i][j] = mfma(b[j], a[i], acc)
// -> acc rows = permuted-N (gates), cols = tokens/vocab rows.
// MODE 0: LSTM layer  -> h = sig(o)*tanh(sig(i)*tanh(g)), write h fp16
// MODE 1: final linear -> out = relu(acc + bias), float4 stores (A gathered
//         via ids from the H1 vocab table)
template <int MODE>
__global__ __launch_bounds__(512, 4) void gemm_kernel(
    const _Float16* __restrict__ A, const int* __restrict__ ids,
    const _Float16* __restrict__ B, const float* __restrict__ bias,
    _Float16* __restrict__ Of, float* __restrict__ Out,
    int nbShift, int nbMask)
{
  __shared__ __align__(16) char smem[24576];        // K-loop 24KB; hT 20KB
  _Float16* sA = (_Float16*)smem;                   // 256 x 32
  _Float16* sB = (_Float16*)(smem + 16384);         // 128 x 32

  const int T = threadIdx.x;
  const int lane = T & 63;
  const int wv = T >> 6;
  const int wrow = wv >> 1, wcol = wv & 1;          // 4 x 2 wave grid
  // XCD-bijective swizzle (all grids % 8 == 0)
  const int nwg = (int)gridDim.x;
  const int bid = (int)blockIdx.x;
  const int swz = (bid & 7) * (nwg >> 3) + (bid >> 3);
  const int mb = swz >> nbShift;
  const int nb = swz & nbMask;
  const size_t t0 = (size_t)mb * 256;
  const int n0 = nb * 128;

  // staging (R2/R3-proven): thread T stages LDS chunk T (lane-contiguous
  // 16B); global k-quad XOR-swizzled by row so frag ds_read_b128 is 2-way.
  const int r0 = T >> 2;                            // 0..127
  const int qg = (T & 3) ^ ((r0 >> 1) & 3);
  size_t sr0 = t0 + r0, sr1 = t0 + 128 + r0;
  if (ids) { sr0 = (size_t)(unsigned)ids[sr0]; sr1 = (size_t)(unsigned)ids[sr1]; }
  const _Float16* gA0 = A + sr0 * 512 + qg * 8;
  const _Float16* gA1 = A + sr1 * 512 + qg * 8;
  const _Float16* gB  = B + (size_t)(n0 + r0) * 512 + qg * 8;

  // fragment read offsets (iter-invariant); un-swizzle with qs
  const int m_ = lane & 15, qf = lane >> 4;
  const int qs = qf ^ ((m_ >> 1) & 3);
  const int offA = wrow * 2048 + m_ * 32 + qs * 8;
  const int offB = wcol * 2048 + m_ * 32 + qs * 8;

  float4v acc[4][4];
#pragma unroll
  for (int i = 0; i < 4; ++i)
#pragma unroll
    for (int j = 0; j < 4; ++j)
      acc[i][j] = (float4v){0.f, 0.f, 0.f, 0.f};

  for (int it = 0; it < 16; ++it) {
    gl2lds16(gA0, sA + T * 8);                      // rows 0..127
    gl2lds16(gA1, sA + 4096 + T * 8);               // rows 128..255
    gl2lds16(gB,  sB + T * 8);
    gA0 += 32; gA1 += 32; gB += 32;
    __syncthreads();

    half8 a[4], b[4];
#pragma unroll
    for (int i = 0; i < 4; ++i) {
      a[i] = *(const half8*)(sA + offA + i * 512);
      b[i] = *(const half8*)(sB + offB + i * 512);
    }
#pragma unroll
    for (int i = 0; i < 4; ++i)
#pragma unroll
      for (int j = 0; j < 4; ++j)
        acc[i][j] = __builtin_amdgcn_mfma_f32_16x16x32_f16(b[j], a[i], acc[i][j], 0, 0, 0);
    __syncthreads();
  }

  // bias: acc rows are permuted-N -> 4 consecutive rows per lane = one float4
  float4v bq[4];
#pragma unroll
  for (int j = 0; j < 4; ++j)
    bq[j] = *(const float4v*)(bias + n0 + wcol * 64 + j * 16 + qf * 4);

  if (MODE == 0) {
    _Float16* hT = (_Float16*)smem;                 // 256 x 40 halfs (80B rows)
    const int ub = wcol * 16 + qf;                  // + j*4 -> unit col 0..31
#pragma unroll
    for (int i = 0; i < 4; ++i) {
      const int trow = wrow * 64 + i * 16 + m_;
#pragma unroll
      for (int j = 0; j < 4; ++j) {
        // regs = gates {i,f,g,o} of unit (ub+j*4); f unused (c_prev=0)
        float yi = acc[i][j][0] + bq[j][0];
        float yg = acc[i][j][2] + bq[j][2];
        float yo = acc[i][j][3] + bq[j][3];
        float cc = sigmoidf_(yi) * tanhf_(yg);
        float hh = sigmoidf_(yo) * tanhf_(cc);
        hT[trow * 40 + ub + j * 4] = (_Float16)hh;
      }
    }
    __syncthreads();
    // readback: thread pair owns one row (32 units = 64B); 2x16B each
    const int tl = T >> 1, hf = T & 1;
    const _Float16* src = hT + tl * 40 + hf * 16;
    uint4v v0 = *(const uint4v*)(src);
    uint4v v1 = *(const uint4v*)(src + 8);
    _Float16* dst = Of + (t0 + tl) * 512 + (size_t)(nb * 32) + hf * 16;
    *(uint4v*)dst = v0;
    *(uint4v*)(dst + 8) = v1;
  } else {
#pragma unroll
    for (int i = 0; i < 4; ++i) {
      const size_t row = t0 + wrow * 64 + i * 16 + m_;
#pragma unroll
      for (int j = 0; j < 4; ++j) {
        float4v v;
#pragma unroll
        for (int r2 = 0; r2 < 4; ++r2)
          v[r2] = fmaxf(acc[i][j][r2] + bq[j][r2], 0.0f);
        *(float4v*)(Out + row * 512 + (size_t)(n0 + wcol * 64 + j * 16 + qf * 4)) = v;
      }
    }
  }
}

extern "C" void kernel_launch(void* const* d_in, const int* in_sizes, int n_in,
                              void* d_out, int out_size, void* d_ws, size_t ws_size,
                              hipStream_t stream) {
  (void)in_sizes; (void)n_in; (void)out_size; (void)ws_size;
  const int*   ids   = (const int*)d_in[0];
  const float* emb   = (const float*)d_in[1];
  const float* W0    = (const float*)d_in[2];
  // d_in[3] = W_hh0 unused (h_prev = 0)
  const float* bi0   = (const float*)d_in[4];
  const float* bh0   = (const float*)d_in[5];
  const float* W1    = (const float*)d_in[6];
  // d_in[7] = W_hh1 unused
  const float* bi1   = (const float*)d_in[8];
  const float* bh1   = (const float*)d_in[9];
  const float* WL    = (const float*)d_in[10];
  const float* blin  = (const float*)d_in[11];
  float* out = (float*)d_out;

  char* ws = (char*)d_ws;
  const size_t MB = 1024 * 1024;
  _Float16* W0f = (_Float16*)(ws);                  // 2 MB
  _Float16* W1f = (_Float16*)(ws + 2 * MB);         // 2 MB
  _Float16* WLf = (_Float16*)(ws + 4 * MB);         // 0.5 MB
  float*    b0p = (float*)(ws + 4 * MB + 512 * 1024);
  float*    b1p = (float*)(ws + 4 * MB + 512 * 1024 + 8192);
  _Float16* Ef  = (_Float16*)(ws + 8 * MB);         // vocab table 51.7MB (64MB slot)
  _Float16* H1f = Ef;                               // Ef dead after layer 0
  _Float16* H0f = (_Float16*)(ws + 72 * MB);        // 64 MB slot
  // total ws use: 136 MB

  // Vocab-table pipeline: layer GEMMs over 50432 padded vocab rows (no
  // gather); final linear gathers H1f rows via ids (65536 tokens).
  prep_kernel<<<13776, 256, 0, stream>>>(emb, W0, bi0, bh0, W1, bi1, bh1, WL,
                                         Ef, W0f, W1f, WLf, b0p, b1p);
  gemm_kernel<0><<<3152, 512, 0, stream>>>(Ef, nullptr, W0f, b0p, H0f, nullptr, 4, 15);
  gemm_kernel<0><<<3152, 512, 0, stream>>>(H0f, nullptr, W1f, b1p, H1f, nullptr, 4, 15);
  gemm_kernel<1><<<1024, 512, 0, stream>>>(H1f, ids, WLf, blin, nullptr, out, 2, 3);
}

// Round 7
// 541.069 us; speedup vs baseline: 1.2290x; 1.0918x over previous
//
#include <hip/hip_runtime.h>
#include <stdint.h>

// LSTM2Encoder: x=emb[ids]; h0=lstm0(x); h1=lstm1(h0); out=relu(h1@Wlin^T+b)
// R9: R8 (vocab-table pipeline, 590us) + double-buffered K-loop with
// counted vmcnt at R8's PROVEN register budget (64 VGPR + 64 AGPR = 128
// -> 16 waves/CU). R4/R7's prefetch failed at 228 regs/wave (7 waves/CU);
// this is the same mechanism at 2x the occupancy. Per iter: STAGE(nxt)
// -> vmcnt(3) [cur landed; nxt's 3 stay in flight] -> s_barrier ->
// ds_reads+MFMA -> s_barrier -> swap. No __syncthreads in the loop (it
// drains vmcnt(0) = ~900cyc cold-HBM A-tile latency every iter — the
// measured 2x gap between R8's 166us and the 79us LDS-pipe floor).
// Everything else (staging swizzle, fragment math, epilogue, XCD swizzle,
// grids) identical to R8.

typedef _Float16 half8 __attribute__((ext_vector_type(8)));
typedef __attribute__((ext_vector_type(4))) float float4v;
typedef __attribute__((ext_vector_type(4))) unsigned int uint4v;

__device__ __forceinline__ float sigmoidf_(float x) { return 1.0f / (1.0f + __expf(-x)); }
__device__ __forceinline__ float tanhf_(float x) { return 1.0f - 2.0f / (__expf(2.0f * x) + 1.0f); }

__device__ __forceinline__ void gl2lds16(const void* g, void* l) {
  __builtin_amdgcn_global_load_lds(
      (const __attribute__((address_space(1))) void*)g,
      (__attribute__((address_space(3))) void*)l, 16, 0, 0);
}

// ---------------- prep: emb->fp16; weights permuted+cast; biases folded ----
// W'[4j+g][k] = W[g*512+j][k]  (g in {i,f,g,o});  b'[4j+g] = b_ih[n]+b_hh[n]
// Also zeroes Ef pad rows [50257,50432) so pad outputs stay finite.
__global__ __launch_bounds__(256) void prep_kernel(
    const float* __restrict__ emb,
    const float* __restrict__ W0, const float* __restrict__ bi0, const float* __restrict__ bh0,
    const float* __restrict__ W1, const float* __restrict__ bi1, const float* __restrict__ bh1,
    const float* __restrict__ WL,
    _Float16* __restrict__ Ef,
    _Float16* __restrict__ W0f, _Float16* __restrict__ W1f, _Float16* __restrict__ WLf,
    float* __restrict__ b0p, float* __restrict__ b1p)
{
  int id = blockIdx.x * 256 + threadIdx.x;
  if (id < 3216448) {                               // emb cast (50257*512/8)
    const float* s = emb + (size_t)id * 8;
    float4v v0 = *(const float4v*)s;
    float4v v1 = *(const float4v*)(s + 4);
    union { _Float16 h[8]; uint4v u; } P;
#pragma unroll
    for (int e = 0; e < 4; ++e) { P.h[e] = (_Float16)v0[e]; P.h[4 + e] = (_Float16)v1[e]; }
    *(uint4v*)(Ef + (size_t)id * 8) = P.u;
  } else if (id < 3347520) {                        // W0 permute+cast (2048*512/8)
    int u = id - 3216448;
    int np = u >> 6, k0 = (u & 63) << 3;
    int n = ((np & 3) << 9) | (np >> 2);
    const float* s = W0 + n * 512 + k0;
    float4v v0 = *(const float4v*)s;
    float4v v1 = *(const float4v*)(s + 4);
    union { _Float16 h[8]; uint4v u; } P;
#pragma unroll
    for (int e = 0; e < 4; ++e) { P.h[e] = (_Float16)v0[e]; P.h[4 + e] = (_Float16)v1[e]; }
    *(uint4v*)(W0f + np * 512 + k0) = P.u;
  } else if (id < 3478592) {                        // W1
    int u = id - 3347520;
    int np = u >> 6, k0 = (u & 63) << 3;
    int n = ((np & 3) << 9) | (np >> 2);
    const float* s = W1 + n * 512 + k0;
    float4v v0 = *(const float4v*)s;
    float4v v1 = *(const float4v*)(s + 4);
    union { _Float16 h[8]; uint4v u; } P;
#pragma unroll
    for (int e = 0; e < 4; ++e) { P.h[e] = (_Float16)v0[e]; P.h[4 + e] = (_Float16)v1[e]; }
    *(uint4v*)(W1f + np * 512 + k0) = P.u;
  } else if (id < 3511360) {                        // WL straight cast (512*512/8)
    int u = id - 3478592;
    const float* s = WL + (size_t)u * 8;
    float4v v0 = *(const float4v*)s;
    float4v v1 = *(const float4v*)(s + 4);
    union { _Float16 h[8]; uint4v u8; } P;
#pragma unroll
    for (int e = 0; e < 4; ++e) { P.h[e] = (_Float16)v0[e]; P.h[4 + e] = (_Float16)v1[e]; }
    *(uint4v*)(WLf + (size_t)u * 8) = P.u8;
  } else if (id < 3513408) {                        // b0 fold+permute
    int np = id - 3511360;
    int n = ((np & 3) << 9) | (np >> 2);
    b0p[np] = bi0[n] + bh0[n];
  } else if (id < 3515456) {                        // b1
    int np = id - 3513408;
    int n = ((np & 3) << 9) | (np >> 2);
    b1p[np] = bi1[n] + bh1[n];
  } else if (id < 3526656) {                        // zero Ef pad rows (175x512)
    int u = id - 3515456;
    *(uint4v*)(Ef + 25731584 + (size_t)u * 8) = (uint4v){0u, 0u, 0u, 0u};
  }
}

// ---------------- fused fp16 GEMM, 256x128 tile, BK=32, dbuf K-loop --------
// 8 waves as 4x2 grid of 64x64 wave tiles. acc[i][j] = mfma(b[j], a[i], acc)
// -> acc rows = permuted-N (gates), cols = tokens/vocab rows.
// MODE 0: LSTM layer  -> h = sig(o)*tanh(sig(i)*tanh(g)), write h fp16
// MODE 1: final linear -> out = relu(acc + bias), float4 stores (A gathered
//         via ids from the H1 vocab table)
template <int MODE>
__global__ __launch_bounds__(512, 4) void gemm_kernel(
    const _Float16* __restrict__ A, const int* __restrict__ ids,
    const _Float16* __restrict__ B, const float* __restrict__ bias,
    _Float16* __restrict__ Of, float* __restrict__ Out,
    int nbShift, int nbMask)
{
  __shared__ __align__(16) char smem[65536];        // 2 x (16KB A + 8KB B); hT 20KB
  const int T = threadIdx.x;
  const int lane = T & 63;
  const int wv = T >> 6;
  const int wrow = wv >> 1, wcol = wv & 1;          // 4 x 2 wave grid
  // XCD-bijective swizzle (all grids % 8 == 0)
  const int nwg = (int)gridDim.x;
  const int bid = (int)blockIdx.x;
  const int swz = (bid & 7) * (nwg >> 3) + (bid >> 3);
  const int mb = swz >> nbShift;
  const int nb = swz & nbMask;
  const size_t t0 = (size_t)mb * 256;
  const int n0 = nb * 128;

  // staging (R2/R3-proven): thread T stages LDS chunk T (lane-contiguous
  // 16B); global k-quad XOR-swizzled by row so frag ds_read_b128 is 2-way.
  const int r0 = T >> 2;                            // 0..127
  const int qg = (T & 3) ^ ((r0 >> 1) & 3);
  size_t sr0 = t0 + r0, sr1 = t0 + 128 + r0;
  if (ids) { sr0 = (size_t)(unsigned)ids[sr0]; sr1 = (size_t)(unsigned)ids[sr1]; }
  const _Float16* gA0 = A + sr0 * 512 + qg * 8;
  const _Float16* gA1 = A + sr1 * 512 + qg * 8;
  const _Float16* gB  = B + (size_t)(n0 + r0) * 512 + qg * 8;

  const int d0 = T * 16;                            // byte offset within buffer
#define STAGE(dst) do { \
    gl2lds16(gA0, (dst) + d0); \
    gl2lds16(gA1, (dst) + 8192 + d0); \
    gl2lds16(gB,  (dst) + 16384 + d0); \
    gA0 += 32; gA1 += 32; gB += 32; } while (0)

  // fragment read offsets (halfs, within a buffer); un-swizzle with qs
  const int m_ = lane & 15, qf = lane >> 4;
  const int qs = qf ^ ((m_ >> 1) & 3);
  const int offA = wrow * 2048 + m_ * 32 + qs * 8;
  const int offB = 8192 + wcol * 2048 + m_ * 32 + qs * 8;

  float4v acc[4][4];
#pragma unroll
  for (int i = 0; i < 4; ++i)
#pragma unroll
    for (int j = 0; j < 4; ++j)
      acc[i][j] = (float4v){0.f, 0.f, 0.f, 0.f};

  // prologue: stage K-tile 0 into buf0 (no wait; first iter's vmcnt covers)
  char* bufc = smem;                                // cur buffer
  char* bufn = smem + 32768;                        // nxt buffer
  STAGE(bufc);

  for (int it = 0; it < 16; ++it) {
    if (it < 15) {
      STAGE(bufn);                                  // prefetch next K-tile
      asm volatile("s_waitcnt vmcnt(3)" ::: "memory");  // cur landed; nxt in flight
    } else {
      asm volatile("s_waitcnt vmcnt(0)" ::: "memory");
    }
    __builtin_amdgcn_sched_barrier(0);
    __builtin_amdgcn_s_barrier();                   // all waves' cur visible

    const _Float16* cur = (const _Float16*)bufc;
    half8 a[4], b[4];
#pragma unroll
    for (int i = 0; i < 4; ++i) {
      a[i] = *(const half8*)(cur + offA + i * 512);
      b[i] = *(const half8*)(cur + offB + i * 512);
    }
#pragma unroll
    for (int i = 0; i < 4; ++i)
#pragma unroll
      for (int j = 0; j < 4; ++j)
        acc[i][j] = __builtin_amdgcn_mfma_f32_16x16x32_f16(b[j], a[i], acc[i][j], 0, 0, 0);
    // MFMAs consumed all ds_reads (compiler lgkm) -> cur safe to overwrite
    __builtin_amdgcn_sched_barrier(0);
    __builtin_amdgcn_s_barrier();
    __builtin_amdgcn_sched_barrier(0);
    char* tc = bufc; bufc = bufn; bufn = tc;
  }
#undef STAGE

  // bias: acc rows are permuted-N -> 4 consecutive rows per lane = one float4
  float4v bq[4];
#pragma unroll
  for (int j = 0; j < 4; ++j)
    bq[j] = *(const float4v*)(bias + n0 + wcol * 64 + j * 16 + qf * 4);

  if (MODE == 0) {
    _Float16* hT = (_Float16*)smem;                 // 256 x 40 halfs (80B rows)
    const int ub = wcol * 16 + qf;                  // + j*4 -> unit col 0..31
#pragma unroll
    for (int i = 0; i < 4; ++i) {
      const int trow = wrow * 64 + i * 16 + m_;
#pragma unroll
      for (int j = 0; j < 4; ++j) {
        // regs = gates {i,f,g,o} of unit (ub+j*4); f unused (c_prev=0)
        float yi = acc[i][j][0] + bq[j][0];
        float yg = acc[i][j][2] + bq[j][2];
        float yo = acc[i][j][3] + bq[j][3];
        float cc = sigmoidf_(yi) * tanhf_(yg);
        float hh = sigmoidf_(yo) * tanhf_(cc);
        hT[trow * 40 + ub + j * 4] = (_Float16)hh;
      }
    }
    __syncthreads();
    // readback: thread pair owns one row (32 units = 64B); 2x16B each
    const int tl = T >> 1, hf = T & 1;
    const _Float16* src = hT + tl * 40 + hf * 16;
    uint4v v0 = *(const uint4v*)(src);
    uint4v v1 = *(const uint4v*)(src + 8);
    _Float16* dst = Of + (t0 + tl) * 512 + (size_t)(nb * 32) + hf * 16;
    *(uint4v*)dst = v0;
    *(uint4v*)(dst + 8) = v1;
  } else {
#pragma unroll
    for (int i = 0; i < 4; ++i) {
      const size_t row = t0 + wrow * 64 + i * 16 + m_;
#pragma unroll
      for (int j = 0; j < 4; ++j) {
        float4v v;
#pragma unroll
        for (int r2 = 0; r2 < 4; ++r2)
          v[r2] = fmaxf(acc[i][j][r2] + bq[j][r2], 0.0f);
        *(float4v*)(Out + row * 512 + (size_t)(n0 + wcol * 64 + j * 16 + qf * 4)) = v;
      }
    }
  }
}

extern "C" void kernel_launch(void* const* d_in, const int* in_sizes, int n_in,
                              void* d_out, int out_size, void* d_ws, size_t ws_size,
                              hipStream_t stream) {
  (void)in_sizes; (void)n_in; (void)out_size; (void)ws_size;
  const int*   ids   = (const int*)d_in[0];
  const float* emb   = (const float*)d_in[1];
  const float* W0    = (const float*)d_in[2];
  // d_in[3] = W_hh0 unused (h_prev = 0)
  const float* bi0   = (const float*)d_in[4];
  const float* bh0   = (const float*)d_in[5];
  const float* W1    = (const float*)d_in[6];
  // d_in[7] = W_hh1 unused
  const float* bi1   = (const float*)d_in[8];
  const float* bh1   = (const float*)d_in[9];
  const float* WL    = (const float*)d_in[10];
  const float* blin  = (const float*)d_in[11];
  float* out = (float*)d_out;

  char* ws = (char*)d_ws;
  const size_t MB = 1024 * 1024;
  _Float16* W0f = (_Float16*)(ws);                  // 2 MB
  _Float16* W1f = (_Float16*)(ws + 2 * MB);         // 2 MB
  _Float16* WLf = (_Float16*)(ws + 4 * MB);         // 0.5 MB
  float*    b0p = (float*)(ws + 4 * MB + 512 * 1024);
  float*    b1p = (float*)(ws + 4 * MB + 512 * 1024 + 8192);
  _Float16* Ef  = (_Float16*)(ws + 8 * MB);         // vocab table 51.7MB (64MB slot)
  _Float16* H1f = Ef;                               // Ef dead after layer 0
  _Float16* H0f = (_Float16*)(ws + 72 * MB);        // 64 MB slot
  // total ws use: 136 MB

  // Vocab-table pipeline: layer GEMMs over 50432 padded vocab rows (no
  // gather); final linear gathers H1f rows via ids (65536 tokens).
  prep_kernel<<<13776, 256, 0, stream>>>(emb, W0, bi0, bh0, W1, bi1, bh1, WL,
                                         Ef, W0f, W1f, WLf, b0p, b1p);
  gemm_kernel<0><<<3152, 512, 0, stream>>>(Ef, nullptr, W0f, b0p, H0f, nullptr, 4, 15);
  gemm_kernel<0><<<3152, 512, 0, stream>>>(H0f, nullptr, W1f, b1p, H1f, nullptr, 4, 15);
  gemm_kernel<1><<<1024, 512, 0, stream>>>(H1f, ids, WLf, blin, nullptr, out, 2, 3);
}